// Round 26
// baseline (103.101 us; speedup 1.0000x reference)
//
#include <hip/hip_runtime.h>
#include <hip/hip_fp16.h>
#include <math.h>

// Capsule dynamic routing, fused-recompute. MFMA einsum, f16 data, fp32 acc.
// B=512, R=1152, C=10, O=16, I=8.
//   iter0: c_ij = 1/10 uniform  -> s0 = 0.1 * sum_r u_hat
//   iter2: b2 = u.(v0+v1)       -> only running vsum kept
// R25 (WIN, 102.4us): softmax max-chain removed (bounded inputs).
// R26 = R25 + ONE change: W pre-converted to f16 ONCE (w16_prep, ~3us)
// into d_ws; acc staging becomes a pure uint4 copy (no packf2 in the
// hot loop; W fetch bytes halve in all 3 passes).

#define R_TOT 1152
#define C_N 10
#define O_N 16
#define I_N 8
#define B_TOT 512
#define RT 64                                   // rtile count (partial slices)
#define RCHB 18                                 // r's per block
#define CHUNK 6                                 // r's per staged chunk
#define NCH 3                                   // chunks per block
#define SEG (B_TOT * C_N * O_N)                 // 81920 floats per partial slice
#define ROWS (C_N * O_N)                        // 160 W rows per r (16B each, f16)
#define CGR (CHUNK * ROWS)                      // 960 rows per chunk
#define WROWS (R_TOT * ROWS)                    // 184320 rows total

typedef _Float16 v8h __attribute__((ext_vector_type(8)));
typedef float v4f __attribute__((ext_vector_type(4)));
typedef unsigned u32x4 __attribute__((ext_vector_type(4)));

// pack two fp32 -> f16x2 (RTN via __float2half)
__device__ __forceinline__ unsigned packf2(float a, float b) {
  unsigned ua = (unsigned)__half_as_ushort(__float2half(a));
  unsigned ub = (unsigned)__half_as_ushort(__float2half(b));
  return ua | (ub << 16);
}

// o-reduce across the 4 og groups (lanes l, l^16, l^32, l^48) on the
// VALU pipe via permlane swaps; falls back to shfl_xor (DS pipe).
__device__ __forceinline__ float oreduce(float a) {
#if __has_builtin(__builtin_amdgcn_permlane16_swap) && \
    __has_builtin(__builtin_amdgcn_permlane32_swap)
  typedef unsigned uv2 __attribute__((ext_vector_type(2)));
  unsigned au = __float_as_uint(a);
  uv2 t = __builtin_amdgcn_permlane16_swap(au, au, false, false);
  const float s16 = __uint_as_float(t.x) + __uint_as_float(t.y);
  unsigned su = __float_as_uint(s16);
  uv2 t2 = __builtin_amdgcn_permlane32_swap(su, su, false, false);
  return __uint_as_float(t2.x) + __uint_as_float(t2.y);
#else
  a += __shfl_xor(a, 16);
  a += __shfl_xor(a, 32);
  return a;
#endif
}

// W row (8 fp32, 32B) -> W16 row (8 f16, one uint4). 184320 rows.
__global__ __launch_bounds__(256) void w16_prep(
    const float* __restrict__ W, uint4* __restrict__ W16)
{
  const int row = blockIdx.x * 256 + threadIdx.x;
  const float4* src = reinterpret_cast<const float4*>(W) + (size_t)row * 2;
  const float4 a = src[0], c = src[1];
  uint4 v;
  v.x = packf2(a.x, a.y); v.y = packf2(a.z, a.w);
  v.z = packf2(c.x, c.y); v.w = packf2(c.z, c.w);
  W16[row] = v;
}

// lane map: bq = lane&15 (b within wave's 16), og = lane>>4 (o-quad).
// thread's b = btile*64 + wave*16 + bq; it holds u[c][o=og*4+j] for all c.
// grid 512: xcd = bid&7, idx = bid>>3; rtile = xcd*8+(idx&7), btile = idx>>3.
template<bool UNIFORM>
__global__ __launch_bounds__(256, 2) void acc_kernel(
    const float* __restrict__ x, const uint4* __restrict__ W16,
    const float* __restrict__ vsum, float* __restrict__ part)
{
  __shared__ uint4 wbuf[2 * CGR];   // 30 KB: two 6-slab f16 chunks, LINEAR

  const int tid  = threadIdx.x;
  const int wave = tid >> 6;
  const int lane = tid & 63;
  const int bq   = lane & 15;
  const int og   = lane >> 4;
  const bool lo32 = (lane < 32);

  const int bid   = blockIdx.x;
  const int xcd   = bid & 7;
  const int idx   = bid >> 3;             // 0..63
  const int rtile = xcd * 8 + (idx & 7);
  const int btile = idx >> 3;             // 0..7

  const int b  = btile * 64 + wave * 16 + bq;
  const int r0 = rtile * RCHB;
  const int og8 = (og & 1) * 8;           // byte offset of this lane's 8B k-slice

  // staging = pure uint4 copy from pre-converted W16 (no conversion)
  auto stage = [&](int ci, int buf) {
    const uint4* src = W16 + (size_t)(r0 + ci * CHUNK) * ROWS;
    #pragma unroll
    for (int k = 0; k < 3; ++k)
      wbuf[buf * CGR + k * 256 + tid] = src[k * 256 + tid];
    if (tid < CGR - 768)
      wbuf[buf * CGR + 768 + tid] = src[768 + tid];
  };

  // x fragment: lanes 0-31 load one aligned float4 of natural-layout x
  // (their 4-elem i-slice) and convert in-register; lanes 32-63 zero.
  auto xload = [&](int r) -> uint2 {
    uint2 v; v.x = 0u; v.y = 0u;
    if (lo32) {
      const float4 xv = *reinterpret_cast<const float4*>(
          &x[((size_t)b * R_TOT + r) * I_N + (og & 1) * 4]);
      v.x = packf2(xv.x, xv.y);
      v.y = packf2(xv.z, xv.w);
    }
    return v;
  };

  float vf[C_N][4];
  if constexpr (!UNIFORM) {
    #pragma unroll
    for (int c = 0; c < C_N; ++c) {
      const float4 tv = *reinterpret_cast<const float4*>(
          &vsum[((size_t)b * C_N + c) * O_N + og * 4]);
      vf[c][0] = tv.x; vf[c][1] = tv.y; vf[c][2] = tv.z; vf[c][3] = tv.w;
    }
  }

  float sacc[C_N][4];
  #pragma unroll
  for (int c = 0; c < C_N; ++c)
    #pragma unroll
    for (int j = 0; j < 4; ++j) sacc[c][j] = 0.0f;

  uint2 xc, xn;
  stage(0, 0);
  xc = xload(r0);
  __syncthreads();

  #pragma unroll 1
  for (int ci = 0; ci < NCH; ++ci) {
    if (ci + 1 < NCH) stage(ci + 1, (ci + 1) & 1);
    const int sb = (ci & 1) * CGR;
    #pragma unroll 1
    for (int rr = 0; rr < CHUNK; ++rr) {
      const int rl = ci * CHUNK + rr;
      const int rn = (rl + 1 < RCHB) ? rl + 1 : rl;
      xn = xload(r0 + rn);                // prefetch next x under compute

      // ---- MFMA einsum: u[c][j] for this lane's (b, og) ----
      u32x4 bxv = {xc.x, xc.y, 0u, 0u};   // B frag: k-slice in regs0-1, rest 0
      const v8h bf = __builtin_bit_cast(v8h, bxv);
      const char* wb = reinterpret_cast<const char*>(&wbuf[sb + rr * ROWS]);

      float u[C_N][4];
      #pragma unroll
      for (int cg = 0; cg < 2; ++cg) {
        uint2 w8[5];
        #pragma unroll
        for (int c5 = 0; c5 < 5; ++c5) { w8[c5].x = 0u; w8[c5].y = 0u; }
        if (lo32) {
          #pragma unroll
          for (int c5 = 0; c5 < 5; ++c5) {
            const int c = cg * 5 + c5;
            w8[c5] = *reinterpret_cast<const uint2*>(
                wb + (c * 16 + bq) * 16 + og8);
          }
        }
        #pragma unroll
        for (int c5 = 0; c5 < 5; ++c5) {
          u32x4 axv = {w8[c5].x, w8[c5].y, 0u, 0u};
          v4f d = __builtin_amdgcn_mfma_f32_16x16x32_f16(
              __builtin_bit_cast(v8h, axv), bf,
              (v4f){0.f, 0.f, 0.f, 0.f}, 0, 0, 0);
          const int c = cg * 5 + c5;
          u[c][0] = d[0]; u[c][1] = d[1]; u[c][2] = d[2]; u[c][3] = d[3];
        }
      }

      // ---- routing update ----
      if constexpr (UNIFORM) {
        #pragma unroll
        for (int c = 0; c < C_N; ++c)
          #pragma unroll
          for (int j = 0; j < 4; ++j) sacc[c][j] += u[c][j];
      } else {
        // softmax WITHOUT max-subtraction: |bij| <~ 1 (bounded inputs),
        // exp can't overflow; ratios mathematically identical.
        float e[C_N];
        float den = 0.0f;
        #pragma unroll
        for (int c = 0; c < C_N; ++c) {
          const float a = u[c][0] * vf[c][0] + u[c][1] * vf[c][1]
                        + u[c][2] * vf[c][2] + u[c][3] * vf[c][3];
          e[c] = __expf(oreduce(a));
          den += e[c];
        }
        const float inv = __builtin_amdgcn_rcpf(den);
        #pragma unroll
        for (int c = 0; c < C_N; ++c) {
          const float cw = e[c] * inv;
          #pragma unroll
          for (int j = 0; j < 4; ++j) sacc[c][j] += cw * u[c][j];
        }
      }
      xc = xn;
    }
    __syncthreads();
  }

  // fp32 float4 partial store
  const float scale = UNIFORM ? 0.1f : 1.0f;
  float* pb = part + (size_t)rtile * SEG;
  #pragma unroll
  for (int c = 0; c < C_N; ++c) {
    float4 v;
    v.x = sacc[c][0] * scale; v.y = sacc[c][1] * scale;
    v.z = sacc[c][2] * scale; v.w = sacc[c][3] * scale;
    *reinterpret_cast<float4*>(
        &pb[((size_t)b * C_N + c) * O_N + og * 4]) = v;
  }
}

// reduce over rtiles + squash over O=16 per (b,c). grid = SEG/64 blocks.
// MODE 0: vsum = v ; MODE 1: vsum += v ; MODE 2: out = v
template<int MODE>
__global__ __launch_bounds__(256) void reduce_squash(
    const float* __restrict__ part, int nrt,
    float* __restrict__ vsum, float* __restrict__ out)
{
  __shared__ float lds[4][64];
  const int tid = threadIdx.x;
  const int l   = tid & 63;
  const int q   = tid >> 6;
  const int j   = blockIdx.x * 64 + l;
  const float* p = part + j;
  float sv = 0.0f;
  #pragma unroll 4
  for (int rt = q; rt < nrt; rt += 4) sv += p[(size_t)rt * SEG];
  lds[q][l] = sv;
  __syncthreads();
  if (q == 0) {
    sv = lds[0][l] + lds[1][l] + lds[2][l] + lds[3][l];
    float sq = sv * sv;
    sq += __shfl_xor(sq, 1);
    sq += __shfl_xor(sq, 2);
    sq += __shfl_xor(sq, 4);
    sq += __shfl_xor(sq, 8);
    const float scale = sq / (1.0f + sq) * rsqrtf(sq + 1e-8f);
    const float v = scale * sv;
    if constexpr (MODE == 0)      vsum[j] = v;
    else if constexpr (MODE == 1) vsum[j] += v;
    else                          out[j] = v;
  }
}

extern "C" void kernel_launch(void* const* d_in, const int* in_sizes, int n_in,
                              void* d_out, int out_size, void* d_ws, size_t ws_size,
                              hipStream_t stream) {
  (void)in_sizes; (void)n_in; (void)out_size; (void)ws_size;
  const float* x = (const float*)d_in[0];
  const float* W = (const float*)d_in[1];
  float* out  = (float*)d_out;   // doubles as vsum; fully rewritten with v2
  float* part = (float*)d_ws;    // RT * SEG floats = 21 MB
  uint4* W16  = reinterpret_cast<uint4*>(part + (size_t)RT * SEG);  // 2.95 MB

  const dim3 blk(256), accGrid(8 * RT), sqGrid(SEG / 64);

  hipLaunchKernelGGL(w16_prep, dim3(WROWS / 256), blk, 0, stream, W, W16);

  // iter 0: uniform coefficients (softmax of zeros)
  hipLaunchKernelGGL((acc_kernel<true>),  accGrid, blk, 0, stream, x, W16, out, part);
  hipLaunchKernelGGL((reduce_squash<0>),  sqGrid,  blk, 0, stream, part, RT, out, out);  // vsum = v0
  // iter 1
  hipLaunchKernelGGL((acc_kernel<false>), accGrid, blk, 0, stream, x, W16, out, part);
  hipLaunchKernelGGL((reduce_squash<1>),  sqGrid,  blk, 0, stream, part, RT, out, out);  // vsum = v0+v1
  // iter 2
  hipLaunchKernelGGL((acc_kernel<false>), accGrid, blk, 0, stream, x, W16, out, part);
  hipLaunchKernelGGL((reduce_squash<2>),  sqGrid,  blk, 0, stream, part, RT, out, out);  // out = v2
}

// Round 27
// 100.953 us; speedup vs baseline: 1.0213x; 1.0213x over previous
//
#include <hip/hip_runtime.h>
#include <hip/hip_fp16.h>
#include <math.h>

// Capsule dynamic routing, fused-recompute. MFMA einsum, f16 data, fp32 acc.
// B=512, R=1152, C=10, O=16, I=8.
//   iter0: c_ij = 1/10 uniform  -> s0 = 0.1 * sum_r u_hat
//   iter2: b2 = u.(v0+v1)       -> only running vsum kept
// R26 post-mortem: W16 pre-conversion null (staging conversion was
// already hidden under compute by the double-buffer). Reverted.
// R27 = R25 + ONE change: UNIFORM pass accumulates IN the MFMA
// (dacc[c] = mfma(a,b,dacc[c]) across all 18 r's) — removes 40
// v_add_f32/iter + the u[] array from pass 0; routing passes unchanged
// (they need per-r u for softmax). Same adds, same order, fp32.

#define R_TOT 1152
#define C_N 10
#define O_N 16
#define I_N 8
#define B_TOT 512
#define RT 64                                   // rtile count (partial slices)
#define RCHB 18                                 // r's per block
#define CHUNK 6                                 // r's per staged chunk
#define NCH 3                                   // chunks per block
#define SEG (B_TOT * C_N * O_N)                 // 81920 floats per partial slice
#define ROWS (C_N * O_N)                        // 160 W rows per r (16B each, f16)
#define CGR (CHUNK * ROWS)                      // 960 rows per chunk

typedef _Float16 v8h __attribute__((ext_vector_type(8)));
typedef float v4f __attribute__((ext_vector_type(4)));
typedef unsigned u32x4 __attribute__((ext_vector_type(4)));

// pack two fp32 -> f16x2 (RTN via __float2half)
__device__ __forceinline__ unsigned packf2(float a, float b) {
  unsigned ua = (unsigned)__half_as_ushort(__float2half(a));
  unsigned ub = (unsigned)__half_as_ushort(__float2half(b));
  return ua | (ub << 16);
}

// o-reduce across the 4 og groups (lanes l, l^16, l^32, l^48) on the
// VALU pipe via permlane swaps; falls back to shfl_xor (DS pipe).
__device__ __forceinline__ float oreduce(float a) {
#if __has_builtin(__builtin_amdgcn_permlane16_swap) && \
    __has_builtin(__builtin_amdgcn_permlane32_swap)
  typedef unsigned uv2 __attribute__((ext_vector_type(2)));
  unsigned au = __float_as_uint(a);
  uv2 t = __builtin_amdgcn_permlane16_swap(au, au, false, false);
  const float s16 = __uint_as_float(t.x) + __uint_as_float(t.y);
  unsigned su = __float_as_uint(s16);
  uv2 t2 = __builtin_amdgcn_permlane32_swap(su, su, false, false);
  return __uint_as_float(t2.x) + __uint_as_float(t2.y);
#else
  a += __shfl_xor(a, 16);
  a += __shfl_xor(a, 32);
  return a;
#endif
}

// lane map: bq = lane&15 (b within wave's 16), og = lane>>4 (o-quad).
// thread's b = btile*64 + wave*16 + bq; it holds u[c][o=og*4+j] for all c.
// grid 512: xcd = bid&7, idx = bid>>3; rtile = xcd*8+(idx&7), btile = idx>>3.
template<bool UNIFORM>
__global__ __launch_bounds__(256, 2) void acc_kernel(
    const float* __restrict__ x, const float* __restrict__ W,
    const float* __restrict__ vsum, float* __restrict__ part)
{
  __shared__ uint4 wbuf[2 * CGR];   // 30 KB: two 6-slab f16 chunks, LINEAR

  const int tid  = threadIdx.x;
  const int wave = tid >> 6;
  const int lane = tid & 63;
  const int bq   = lane & 15;
  const int og   = lane >> 4;
  const bool lo32 = (lane < 32);

  const int bid   = blockIdx.x;
  const int xcd   = bid & 7;
  const int idx   = bid >> 3;             // 0..63
  const int rtile = xcd * 8 + (idx & 7);
  const int btile = idx >> 3;             // 0..7

  const int b  = btile * 64 + wave * 16 + bq;
  const int r0 = rtile * RCHB;
  const int og8 = (og & 1) * 8;           // byte offset of this lane's 8B k-slice

  // linear staging: chunk rows are contiguous in W (6 consecutive r slabs)
  auto stage = [&](int ci, int buf) {
    const int rbase = r0 + ci * CHUNK;
    #pragma unroll 1
    for (int g = tid; g < CGR; g += 256) {
      const float4* wsrc = reinterpret_cast<const float4*>(W)
                         + ((size_t)rbase * ROWS + g) * 2;
      const float4 a = wsrc[0], c4 = wsrc[1];
      uint4 v;
      v.x = packf2(a.x, a.y);  v.y = packf2(a.z, a.w);
      v.z = packf2(c4.x, c4.y); v.w = packf2(c4.z, c4.w);
      wbuf[buf * CGR + g] = v;
    }
  };

  // x fragment: lanes 0-31 load one aligned float4 of natural-layout x
  // (their 4-elem i-slice) and convert in-register; lanes 32-63 zero.
  auto xload = [&](int r) -> uint2 {
    uint2 v; v.x = 0u; v.y = 0u;
    if (lo32) {
      const float4 xv = *reinterpret_cast<const float4*>(
          &x[((size_t)b * R_TOT + r) * I_N + (og & 1) * 4]);
      v.x = packf2(xv.x, xv.y);
      v.y = packf2(xv.z, xv.w);
    }
    return v;
  };

  float vf[C_N][4];
  if constexpr (!UNIFORM) {
    #pragma unroll
    for (int c = 0; c < C_N; ++c) {
      const float4 tv = *reinterpret_cast<const float4*>(
          &vsum[((size_t)b * C_N + c) * O_N + og * 4]);
      vf[c][0] = tv.x; vf[c][1] = tv.y; vf[c][2] = tv.z; vf[c][3] = tv.w;
    }
  }

  float sacc[C_N][4];      // routing-pass accumulator (VALU)
  v4f dacc[C_N];           // UNIFORM-pass accumulator (lives in MFMA C/D)
  #pragma unroll
  for (int c = 0; c < C_N; ++c) {
    #pragma unroll
    for (int j = 0; j < 4; ++j) sacc[c][j] = 0.0f;
    dacc[c] = (v4f){0.f, 0.f, 0.f, 0.f};
  }

  uint2 xc, xn;
  stage(0, 0);
  xc = xload(r0);
  __syncthreads();

  #pragma unroll 1
  for (int ci = 0; ci < NCH; ++ci) {
    if (ci + 1 < NCH) stage(ci + 1, (ci + 1) & 1);
    const int sb = (ci & 1) * CGR;
    #pragma unroll 1
    for (int rr = 0; rr < CHUNK; ++rr) {
      const int rl = ci * CHUNK + rr;
      const int rn = (rl + 1 < RCHB) ? rl + 1 : rl;
      xn = xload(r0 + rn);                // prefetch next x under compute

      // ---- MFMA einsum for this r-slab ----
      u32x4 bxv = {xc.x, xc.y, 0u, 0u};   // B frag: k-slice in regs0-1, rest 0
      const v8h bf = __builtin_bit_cast(v8h, bxv);
      const char* wb = reinterpret_cast<const char*>(&wbuf[sb + rr * ROWS]);

      if constexpr (UNIFORM) {
        // accumulate directly in the MFMA C/D operand across all r's
        #pragma unroll
        for (int cg = 0; cg < 2; ++cg) {
          uint2 w8[5];
          #pragma unroll
          for (int c5 = 0; c5 < 5; ++c5) { w8[c5].x = 0u; w8[c5].y = 0u; }
          if (lo32) {
            #pragma unroll
            for (int c5 = 0; c5 < 5; ++c5) {
              const int c = cg * 5 + c5;
              w8[c5] = *reinterpret_cast<const uint2*>(
                  wb + (c * 16 + bq) * 16 + og8);
            }
          }
          #pragma unroll
          for (int c5 = 0; c5 < 5; ++c5) {
            const int c = cg * 5 + c5;
            u32x4 axv = {w8[c5].x, w8[c5].y, 0u, 0u};
            dacc[c] = __builtin_amdgcn_mfma_f32_16x16x32_f16(
                __builtin_bit_cast(v8h, axv), bf, dacc[c], 0, 0, 0);
          }
        }
      } else {
        float u[C_N][4];
        #pragma unroll
        for (int cg = 0; cg < 2; ++cg) {
          uint2 w8[5];
          #pragma unroll
          for (int c5 = 0; c5 < 5; ++c5) { w8[c5].x = 0u; w8[c5].y = 0u; }
          if (lo32) {
            #pragma unroll
            for (int c5 = 0; c5 < 5; ++c5) {
              const int c = cg * 5 + c5;
              w8[c5] = *reinterpret_cast<const uint2*>(
                  wb + (c * 16 + bq) * 16 + og8);
            }
          }
          #pragma unroll
          for (int c5 = 0; c5 < 5; ++c5) {
            u32x4 axv = {w8[c5].x, w8[c5].y, 0u, 0u};
            v4f d = __builtin_amdgcn_mfma_f32_16x16x32_f16(
                __builtin_bit_cast(v8h, axv), bf,
                (v4f){0.f, 0.f, 0.f, 0.f}, 0, 0, 0);
            const int c = cg * 5 + c5;
            u[c][0] = d[0]; u[c][1] = d[1]; u[c][2] = d[2]; u[c][3] = d[3];
          }
        }

        // softmax WITHOUT max-subtraction: |bij| <~ 1 (bounded inputs),
        // exp can't overflow; ratios mathematically identical.
        float e[C_N];
        float den = 0.0f;
        #pragma unroll
        for (int c = 0; c < C_N; ++c) {
          const float a = u[c][0] * vf[c][0] + u[c][1] * vf[c][1]
                        + u[c][2] * vf[c][2] + u[c][3] * vf[c][3];
          e[c] = __expf(oreduce(a));
          den += e[c];
        }
        const float inv = __builtin_amdgcn_rcpf(den);
        #pragma unroll
        for (int c = 0; c < C_N; ++c) {
          const float cw = e[c] * inv;
          #pragma unroll
          for (int j = 0; j < 4; ++j) sacc[c][j] += cw * u[c][j];
        }
      }
      xc = xn;
    }
    __syncthreads();
  }

  if constexpr (UNIFORM) {
    #pragma unroll
    for (int c = 0; c < C_N; ++c)
      #pragma unroll
      for (int j = 0; j < 4; ++j) sacc[c][j] = dacc[c][j];
  }

  // fp32 float4 partial store
  const float scale = UNIFORM ? 0.1f : 1.0f;
  float* pb = part + (size_t)rtile * SEG;
  #pragma unroll
  for (int c = 0; c < C_N; ++c) {
    float4 v;
    v.x = sacc[c][0] * scale; v.y = sacc[c][1] * scale;
    v.z = sacc[c][2] * scale; v.w = sacc[c][3] * scale;
    *reinterpret_cast<float4*>(
        &pb[((size_t)b * C_N + c) * O_N + og * 4]) = v;
  }
}

// reduce over rtiles + squash over O=16 per (b,c). grid = SEG/64 blocks.
// MODE 0: vsum = v ; MODE 1: vsum += v ; MODE 2: out = v
template<int MODE>
__global__ __launch_bounds__(256) void reduce_squash(
    const float* __restrict__ part, int nrt,
    float* __restrict__ vsum, float* __restrict__ out)
{
  __shared__ float lds[4][64];
  const int tid = threadIdx.x;
  const int l   = tid & 63;
  const int q   = tid >> 6;
  const int j   = blockIdx.x * 64 + l;
  const float* p = part + j;
  float sv = 0.0f;
  #pragma unroll 4
  for (int rt = q; rt < nrt; rt += 4) sv += p[(size_t)rt * SEG];
  lds[q][l] = sv;
  __syncthreads();
  if (q == 0) {
    sv = lds[0][l] + lds[1][l] + lds[2][l] + lds[3][l];
    float sq = sv * sv;
    sq += __shfl_xor(sq, 1);
    sq += __shfl_xor(sq, 2);
    sq += __shfl_xor(sq, 4);
    sq += __shfl_xor(sq, 8);
    const float scale = sq / (1.0f + sq) * rsqrtf(sq + 1e-8f);
    const float v = scale * sv;
    if constexpr (MODE == 0)      vsum[j] = v;
    else if constexpr (MODE == 1) vsum[j] += v;
    else                          out[j] = v;
  }
}

extern "C" void kernel_launch(void* const* d_in, const int* in_sizes, int n_in,
                              void* d_out, int out_size, void* d_ws, size_t ws_size,
                              hipStream_t stream) {
  (void)in_sizes; (void)n_in; (void)out_size; (void)ws_size;
  const float* x = (const float*)d_in[0];
  const float* W = (const float*)d_in[1];
  float* out  = (float*)d_out;   // doubles as vsum; fully rewritten with v2
  float* part = (float*)d_ws;    // RT * SEG floats = 21 MB

  const dim3 blk(256), accGrid(8 * RT), sqGrid(SEG / 64);

  // iter 0: uniform coefficients (softmax of zeros)
  hipLaunchKernelGGL((acc_kernel<true>),  accGrid, blk, 0, stream, x, W, out, part);
  hipLaunchKernelGGL((reduce_squash<0>),  sqGrid,  blk, 0, stream, part, RT, out, out);  // vsum = v0
  // iter 1
  hipLaunchKernelGGL((acc_kernel<false>), accGrid, blk, 0, stream, x, W, out, part);
  hipLaunchKernelGGL((reduce_squash<1>),  sqGrid,  blk, 0, stream, part, RT, out, out);  // vsum = v0+v1
  // iter 2
  hipLaunchKernelGGL((acc_kernel<false>), accGrid, blk, 0, stream, x, W, out, part);
  hipLaunchKernelGGL((reduce_squash<2>),  sqGrid,  blk, 0, stream, part, RT, out, out);  // out = v2
}